// Round 4
// baseline (159.795 us; speedup 1.0000x reference)
//
#include <hip/hip_runtime.h>
#include <hip/hip_bf16.h>

// ---------------------------------------------------------------------------
// InferCellV2 R4: bf16 MFMA implicit GEMM, LDS-staged, XOR-swizzled layout,
// software-pipelined tap loop.
// Global activation layout: zero-padded NHWC bf16 [B][34][34][64], 16B channel
// chunks permuted: chunk cb of pixel p at p*128 + ((cb^(p&7))*16). Weights
// wt[l][tap][o][i] swizzled by o&7. => linear global_load_lds staging AND
// conflict-free ds_read_b128 fragments (verified R3: SQ_LDS_BANK_CONFLICT=0).
// conv_stage R4 structure: 256 thr / 4 waves / 8 output rows / grid 512
// (2 blocks/CU). Per src: A staged ONCE (10 rows, 43520 B — kills the R3 3x
// per-ky restage). B staged per single tap (8 KB) into a 2-deep ring,
// prefetched one tap ahead so the pre-barrier vmcnt drain finds it complete.
// LDS = 43520 + 2*8192 = 59904 B (static). Wave tile 64px x 64oc, 64 acc.
// ---------------------------------------------------------------------------

typedef __bf16 bf16x8 __attribute__((ext_vector_type(8)));
typedef float floatx4 __attribute__((ext_vector_type(4)));
typedef unsigned int uint32;

#define PADW 34
#define PIMG (PADW * PADW)
#define ROWB (PADW * 64 * 2)        // 4352 B per padded NHWC row
#define A_LDS (10 * ROWB)           // 43520 (10 rows: 8 outputs + 2 halo)
#define TAPB (64 * 64 * 2)          // 8192 B per weight tap
#define A_CHUNKS (A_LDS / 16)       // 2720 = 10*256 + 160

__device__ __forceinline__ void gld16(const char* g, char* l) {
    __builtin_amdgcn_global_load_lds(
        (const __attribute__((address_space(1))) uint32*)g,
        (__attribute__((address_space(3))) uint32*)l, 16, 0, 0);
}

// ---------------- weight prep: fold scale, transpose, swizzle ---------------
__global__ void prep_weights(const float* __restrict__ a1,
                             const float* __restrict__ a2,
                             const float* __restrict__ W,
                             __hip_bfloat16* __restrict__ wt) {
    int idx = blockIdx.x * 256 + threadIdx.x;   // 6*9*64*64 = 221184 exact
    int i = idx & 63;
    int o = (idx >> 6) & 63;
    int rest = idx >> 12;
    int t = rest % 9;
    int l = rest / 9;
    int ji = i >> 3, jo = o >> 3;
    float ain = 0.f, aout = 0.f;
#pragma unroll
    for (int j = 0; j < 8; ++j) {
        ain  += (j >= ji) ? a1[j] : 0.f;
        aout += (j >= jo) ? a2[j] : 0.f;
    }
    float v = W[(size_t)((l * 64 + o) * 64 + i) * 9 + t] * ain * aout;
    size_t e = (size_t)(l * 9 + t) * 4096 + o * 64 +
               ((((i >> 3) ^ (o & 7)) << 3) + (i & 7));
    wt[e] = __float2bfloat16(v);
}

// ---------------- relu(x) -> padded swizzled NHWC bf16 ----------------------
__global__ void relu_pad(const float* __restrict__ in,
                         __hip_bfloat16* __restrict__ r0) {
    __shared__ float tile[32][65];
    int b = blockIdx.x >> 5, y = blockIdx.x & 31;
    int tid = threadIdx.x;
    int x = tid & 31, c0 = tid >> 5;
    const float* ip = in + ((size_t)b * 64 * 32 + y) * 32 + x;
#pragma unroll
    for (int cc = 0; cc < 8; ++cc) {
        int c = cc * 8 + c0;
        tile[x][c] = fmaxf(ip[(size_t)c * 1024], 0.f);
    }
    __syncthreads();
    int o = tid & 63, xg = tid >> 6;
    int p0 = (b * PADW + y + 1) * PADW + 1;
#pragma unroll
    for (int xx = 0; xx < 8; ++xx) {
        int xq = xx * 4 + xg;
        int p = p0 + xq;
        size_t e = (size_t)p * 64 + ((((o >> 3) ^ (p & 7)) << 3) + (o & 7));
        r0[e] = __float2bfloat16(tile[xq][o]);
    }
}

// ---------------- zero halo ring (whole pixels; swizzle-agnostic) -----------
__global__ void zero_halo(__hip_bfloat16* r0, __hip_bfloat16* r1,
                          __hip_bfloat16* r2) {
    int b = blockIdx.x;
    int tid = threadIdx.x;
    __hip_bfloat16* bufs[3] = {r0, r1, r2};
#pragma unroll
    for (int f = 0; f < 3; ++f) {
        uint32* buf = (uint32*)(bufs[f] + (size_t)b * PIMG * 64);
        for (int idx = tid; idx < 132 * 32; idx += 256) {
            int slot = idx >> 5, u = idx & 31;
            int yy, xx;
            if (slot < 34)      { yy = 0;  xx = slot; }
            else if (slot < 68) { yy = 33; xx = slot - 34; }
            else { int s2 = slot - 68; yy = 1 + (s2 >> 1); xx = (s2 & 1) * 33; }
            buf[(size_t)(yy * PADW + xx) * 32 + u] = 0u;
        }
    }
}

// ---------------- conv stage: pipelined tap loop ----------------------------
// Block: image b = blk>>2, rows y0=(blk&3)*8 .. y0+7. Wave wv: rows y0+2wv,+1.
// A-frag: l15 = px, quad*8+q*32 = in-ch. B-frag: l15 = oc. C/D: M=quad*4+r.
template <int NSRC, bool FINAL>
__global__ __launch_bounds__(256) void conv_stage(
    const __hip_bfloat16* __restrict__ s0,
    const __hip_bfloat16* __restrict__ s1,
    const __hip_bfloat16* __restrict__ s2,
    const __hip_bfloat16* __restrict__ wt,
    void* __restrict__ dstv, int l0) {
    __shared__ char smem[A_LDS + 2 * TAPB];     // 59904 B
    int tid = threadIdx.x;
    int wv = tid >> 6, lane = tid & 63;
    int quad = lane >> 4, l15 = lane & 15;
    int blk = blockIdx.x;
    int b = blk >> 2, y0 = (blk & 3) << 3;

    const char* srcs[3] = {(const char*)s0, (const char*)s1, (const char*)s2};
    const char* gW = (const char*)wt + (size_t)l0 * 9 * (size_t)TAPB;

    auto stage_A = [&](int s) {
        const char* gA = srcs[s] + (size_t)(b * PADW + y0) * PADW * 128;
#pragma unroll
        for (int it = 0; it < 11; ++it) {
            int c = it * 256 + tid;
            if (it < 10 || tid < 160)   // A_CHUNKS = 2720 (exec-masked tail ok)
                gld16(gA + (size_t)c * 16, smem + (it * 256 + wv * 64) * 16);
        }
    };
    auto stage_B = [&](int T) {         // tap T (= s*9 + ky*3 + kx) -> ring T&1
        const char* gB = gW + (size_t)T * TAPB;
        char* dst = smem + A_LDS + (T & 1) * TAPB;
#pragma unroll
        for (int it = 0; it < 2; ++it)
            gld16(gB + (size_t)(it * 256 + tid) * 16,
                  dst + (it * 256 + wv * 64) * 16);
    };

    floatx4 acc[4][4];
#pragma unroll
    for (int m = 0; m < 4; ++m)
#pragma unroll
        for (int n = 0; n < 4; ++n) acc[m][n] = (floatx4){0.f, 0.f, 0.f, 0.f};

    stage_A(0);
    stage_B(0);
    __syncthreads();                    // A(src0) + B(tap0) ready

#pragma unroll
    for (int T = 0; T < 9 * NSRC; ++T) {
        int s = T / 9, tl = T % 9, ky = tl / 3, kx = tl % 3, buf = T & 1;
        if (T + 1 < 9 * NSRC) stage_B(T + 1);   // prefetch into other ring slot

#pragma unroll
        for (int q = 0; q < 2; ++q) {
            bf16x8 Af[4], Bf[4];
#pragma unroll
            for (int m = 0; m < 4; ++m) {
                int arow = 2 * wv + (m >> 1) + ky;      // LDS row 0..9
                int apx  = ((m & 1) << 4) + l15 + kx;   // 0..33
                int R = b * PADW + y0 + arow;           // global padded row
                int slot = ((q << 2) + quad) ^ ((2 * R + apx) & 7);
                Af[m] = *(const bf16x8*)(smem + arow * ROWB +
                                         apx * 128 + slot * 16);
            }
#pragma unroll
            for (int n = 0; n < 4; ++n) {
                int o = (n << 4) + l15;
                int slot = ((q << 2) + quad) ^ (l15 & 7);
                Bf[n] = *(const bf16x8*)(smem + A_LDS + buf * TAPB +
                                         o * 128 + slot * 16);
            }
#pragma unroll
            for (int m = 0; m < 4; ++m)
#pragma unroll
                for (int n = 0; n < 4; ++n)
                    acc[m][n] = __builtin_amdgcn_mfma_f32_16x16x32_bf16(
                        Af[m], Bf[n], acc[m][n], 0, 0, 0);
        }

        if (T + 1 < 9 * NSRC) {
            __syncthreads();            // B(T+1) drained; B[buf]/A reads done
            if (tl == 8) {              // src boundary: swap A tile (only stall)
                stage_A(s + 1);
                __syncthreads();
            }
        }
    }

    // Epilogue. M(pixel) = quad*4+r (+16 for odd m-tile), N(oc) = n*16+l15.
    if (FINAL) {
        float* out = (float*)dstv;   // fp32 NCHW [128][64][32][32]
#pragma unroll
        for (int m = 0; m < 4; ++m) {
            int row = y0 + 2 * wv + (m >> 1);
#pragma unroll
            for (int n = 0; n < 4; ++n) {
                int o = (n << 4) + l15;
#pragma unroll
                for (int r = 0; r < 4; ++r) {
                    int x = ((m & 1) << 4) + (quad << 2) + r;
                    out[(((size_t)b * 64 + o) * 32 + row) * 32 + x] = acc[m][n][r];
                }
            }
        }
    } else {
        __hip_bfloat16* out = (__hip_bfloat16*)dstv;  // relu -> swizzled NHWC
#pragma unroll
        for (int m = 0; m < 4; ++m) {
            int row = y0 + 2 * wv + (m >> 1);
#pragma unroll
            for (int n = 0; n < 4; ++n) {
                int o = (n << 4) + l15;
#pragma unroll
                for (int r = 0; r < 4; ++r) {
                    int x = ((m & 1) << 4) + (quad << 2) + r;
                    int p = (b * PADW + row + 1) * PADW + x + 1;
                    float v = fmaxf(acc[m][n][r], 0.f);
                    size_t e = (size_t)p * 64 +
                               ((((o >> 3) ^ (p & 7)) << 3) + (o & 7));
                    out[e] = __float2bfloat16(v);
                }
            }
        }
    }
}

// ---------------------------------------------------------------------------
extern "C" void kernel_launch(void* const* d_in, const int* in_sizes, int n_in,
                              void* d_out, int out_size, void* d_ws,
                              size_t ws_size, hipStream_t stream) {
    const float* inputs  = (const float*)d_in[0];
    const float* alphas1 = (const float*)d_in[1];
    const float* alphas2 = (const float*)d_in[2];
    const float* W       = (const float*)d_in[3];
    char* ws = (char*)d_ws;

    __hip_bfloat16* wt = (__hip_bfloat16*)(ws);                     // 442 KB
    __hip_bfloat16* r0 = (__hip_bfloat16*)(ws + ((size_t)1 << 20)); // 18.9 MB
    __hip_bfloat16* r1 = (__hip_bfloat16*)(ws + ((size_t)20 << 20));
    __hip_bfloat16* r2 = (__hip_bfloat16*)(ws + ((size_t)40 << 20));
    float* out = (float*)d_out;

    prep_weights<<<864, 256, 0, stream>>>(alphas1, alphas2, W, wt);
    relu_pad<<<128 * 32, 256, 0, stream>>>(inputs, r0);
    zero_halo<<<128, 256, 0, stream>>>(r0, r1, r2);

    conv_stage<1, false><<<512, 256, 0, stream>>>(r0, r1, r2, wt, (void*)r1, 0);
    conv_stage<2, false><<<512, 256, 0, stream>>>(r0, r1, r2, wt, (void*)r2, 1);
    conv_stage<3, true ><<<512, 256, 0, stream>>>(r0, r1, r2, wt, (void*)out, 3);
}